// Round 1
// baseline (180.047 us; speedup 1.0000x reference)
//
#include <hip/hip_runtime.h>

#define OUT_PIX   25165824    // 8*3*1024*1024
#define SPLINE_OFF 25165824   // splines output offset (6120 floats follow)
#define STEP_F (1.0f/9.0f)

// ---------------------------------------------------------------------------
// Resize: jax.image.resize bilinear antialias, 1024 -> 256 (scale 0.25).
// Separable triangle kernel, 8 taps at stride 4, raw weights
// {1,3,5,7,7,5,3,1}/8, normalized by sum of valid taps (4.0 interior).
// ---------------------------------------------------------------------------
__global__ __launch_bounds__(256) void resize_v_k(const float* __restrict__ x,
                                                  float* __restrict__ tmp) {
    int idx = blockIdx.x * 256 + threadIdx.x;        // 24*256*1024
    int col  = idx & 1023;
    int orow = (idx >> 10) & 255;
    int plane = idx >> 18;
    const float* p = x + (size_t)plane * 1048576 + col;
    int r0 = 4 * orow - 2;
    const float W[8] = {0.125f,0.375f,0.625f,0.875f,0.875f,0.625f,0.375f,0.125f};
    float acc = 0.f;
    if (r0 >= 0 && r0 + 7 <= 1023) {
        #pragma unroll
        for (int k = 0; k < 8; k++)
            acc = fmaf(p[(size_t)(r0 + k) * 1024], W[k] * 0.25f, acc);
    } else {
        float wsum = 0.f;
        #pragma unroll
        for (int k = 0; k < 8; k++) {
            int r = r0 + k;
            if (r >= 0 && r < 1024) { acc = fmaf(p[(size_t)r * 1024], W[k], acc); wsum += W[k]; }
        }
        acc /= wsum;
    }
    tmp[idx] = acc;
}

__global__ __launch_bounds__(256) void resize_h_k(const float* __restrict__ tmp,
                                                  float* __restrict__ sm) {
    int idx = blockIdx.x * 256 + threadIdx.x;        // 24*256*256
    int ocol = idx & 255;
    int row  = (idx >> 8) & 255;
    int plane = idx >> 16;
    const float* p = tmp + (size_t)plane * 262144 + (size_t)row * 1024;
    int c0 = 4 * ocol - 2;
    const float W[8] = {0.125f,0.375f,0.625f,0.875f,0.875f,0.625f,0.375f,0.125f};
    float acc = 0.f;
    if (c0 >= 0 && c0 + 7 <= 1023) {
        #pragma unroll
        for (int k = 0; k < 8; k++)
            acc = fmaf(p[c0 + k], W[k] * 0.25f, acc);
    } else {
        float wsum = 0.f;
        #pragma unroll
        for (int k = 0; k < 8; k++) {
            int c = c0 + k;
            if (c >= 0 && c < 1024) { acc = fmaf(p[c], W[k], acc); wsum += W[k]; }
        }
        acc /= wsum;
    }
    sm[idx] = acc;
}

// ---------------------------------------------------------------------------
// Direct 3x3 stride-2 VALID conv + bias + ReLU.
//  - INBN: apply previous layer's batchnorm (scale/shift from accumulated
//          sum/sumsq stats) to the input on load.
//  - STATS: accumulate per-output-channel sum & sumsq of the ReLU output
//           (for this layer's BN, consumed by the NEXT kernel).
//  - SPATIAL: also write per-(b,co) spatial sum (requires gridDim.x == 1).
// blockIdx.y = b*COUT + co.
// ---------------------------------------------------------------------------
template<int CIN, int COUT, int INW, int OUTW, int BLOCK, bool INBN, bool STATS, bool SPATIAL>
__global__ __launch_bounds__(BLOCK) void conv_k(
    const float* __restrict__ in, const float* __restrict__ w,
    const float* __restrict__ bias,
    const float* __restrict__ g, const float* __restrict__ be,
    const float* __restrict__ inStats, float inInvN,
    float* __restrict__ out,
    float* __restrict__ gsum, float* __restrict__ gsumsq,
    float* __restrict__ spat)
{
    __shared__ float wsm[CIN * 9];
    __shared__ float scs[CIN];
    __shared__ float shs[CIN];
    __shared__ float red[2][BLOCK / 64];

    const int tid = threadIdx.x;
    const int bc = blockIdx.y;
    const int b  = bc / COUT;
    const int co = bc % COUT;

    for (int i = tid; i < CIN * 9; i += BLOCK) wsm[i] = w[co * CIN * 9 + i];
    if constexpr (INBN) {
        for (int ci = tid; ci < CIN; ci += BLOCK) {
            float s  = inStats[ci];
            float sq = inStats[CIN + ci];
            float m  = s * inInvN;
            float v  = sq * inInvN - m * m;
            float sc = g[ci] * rsqrtf(v + 1e-5f);
            scs[ci] = sc;
            shs[ci] = be[ci] - m * sc;
        }
    }
    __syncthreads();

    const int npix = OUTW * OUTW;
    const int p = blockIdx.x * BLOCK + tid;
    float val = 0.f;
    if (p < npix) {
        int oh = p / OUTW, ow = p % OUTW;
        float acc = bias[co];
        const float* ib = in + (size_t)(b * CIN) * INW * INW + (size_t)(2 * oh) * INW + 2 * ow;
        for (int ci = 0; ci < CIN; ci++) {
            const float* ip = ib + (size_t)ci * INW * INW;
            float sc = 1.f, sh = 0.f;
            if constexpr (INBN) { sc = scs[ci]; sh = shs[ci]; }
            #pragma unroll
            for (int kh = 0; kh < 3; kh++) {
                const float* r = ip + kh * INW;
                float x0 = r[0], x1 = r[1], x2 = r[2];
                if constexpr (INBN) {
                    x0 = fmaf(x0, sc, sh); x1 = fmaf(x1, sc, sh); x2 = fmaf(x2, sc, sh);
                }
                acc = fmaf(x0, wsm[ci * 9 + kh * 3 + 0], acc);
                acc = fmaf(x1, wsm[ci * 9 + kh * 3 + 1], acc);
                acc = fmaf(x2, wsm[ci * 9 + kh * 3 + 2], acc);
            }
        }
        val = fmaxf(acc, 0.f);
        out[(size_t)bc * npix + p] = val;
    }

    if constexpr (STATS) {
        float s = val, sq = val * val;
        #pragma unroll
        for (int off = 32; off > 0; off >>= 1) {
            s  += __shfl_down(s, off);
            sq += __shfl_down(sq, off);
        }
        int wid = tid >> 6, lane = tid & 63;
        if (lane == 0) { red[0][wid] = s; red[1][wid] = sq; }
        __syncthreads();
        if (tid == 0) {
            float ts = 0.f, tq = 0.f;
            #pragma unroll
            for (int i = 0; i < BLOCK / 64; i++) { ts += red[0][i]; tq += red[1][i]; }
            atomicAdd(&gsum[co], ts);
            atomicAdd(&gsumsq[co], tq);
            if constexpr (SPATIAL) spat[bc] = ts;   // gridDim.x == 1 here
        }
    }
}

// ---------------------------------------------------------------------------
// Single-block: BN5 finalize -> spatial mean -> fc1(ReLU) -> fc2 -> +identity
// -> natural cubic spline coefficients (Thomas solve) -> write coeffs + the
// 255-point "splines" output.
// ---------------------------------------------------------------------------
__global__ __launch_bounds__(256) void fc_spline_k(
    const float* __restrict__ spat5, const float* __restrict__ stats5,
    const float* __restrict__ g5, const float* __restrict__ be5,
    const float* __restrict__ fc1w, const float* __restrict__ fc1b,
    const float* __restrict__ fc2w, const float* __restrict__ fc2b,
    float* __restrict__ coeff_out, float* __restrict__ splines_out)
{
    __shared__ float sc5[128], sh5[128];
    __shared__ float h[1024];     // [b][c] b<8, c<128
    __shared__ float h1v[1024];
    __shared__ float ysn[240];    // [bc][10], bc = b*3+cch
    __shared__ float coef[24][36];

    const int t = threadIdx.x;

    if (t < 128) {
        float m = stats5[t] * (1.f / 392.f);
        float v = stats5[128 + t] * (1.f / 392.f) - m * m;
        float sc = g5[t] * rsqrtf(v + 1e-5f);
        sc5[t] = sc;
        sh5[t] = be5[t] - m * sc;
    }
    __syncthreads();

    for (int i = t; i < 1024; i += 256) {
        int c = i & 127;
        h[i] = fmaf(sc5[c], spat5[i] * (1.f / 49.f), sh5[c]);
    }
    __syncthreads();

    for (int i = t; i < 1024; i += 256) {
        int b = i >> 7, j = i & 127;
        float acc = fc1b[j];
        for (int c = 0; c < 128; c++)
            acc = fmaf(h[(b << 7) + c], fc1w[(j << 7) + c], acc);
        h1v[i] = fmaxf(acc, 0.f);
    }
    __syncthreads();

    if (t < 240) {
        int b = t / 30, k = t % 30;
        float acc = fc2b[k];
        for (int j = 0; j < 128; j++)
            acc = fmaf(h1v[(b << 7) + j], fc2w[(k << 7) + j], acc);
        ysn[t] = acc + (float)(k % 10) * STEP_F;   // + identity ramp
    }
    __syncthreads();

    if (t < 24) {
        float y[10];
        #pragma unroll
        for (int i = 0; i < 10; i++) y[i] = ysn[t * 10 + i];
        // Thomas solve: M[i-1] + 4 M[i] + M[i+1] = 486*(y[i-1]-2y[i]+y[i+1]),
        // i=1..8, M[0]=M[9]=0   (486 = 6/h^2, h = 1/9)
        float rhs[9], cp[9], dp[9];
        #pragma unroll
        for (int i = 1; i <= 8; i++)
            rhs[i] = 486.f * (y[i - 1] - 2.f * y[i] + y[i + 1]);
        cp[1] = 0.25f; dp[1] = rhs[1] * 0.25f;
        #pragma unroll
        for (int i = 2; i <= 8; i++) {
            float m = 1.f / (4.f - cp[i - 1]);
            cp[i] = m;
            dp[i] = (rhs[i] - dp[i - 1]) * m;
        }
        float M[10];
        M[0] = 0.f; M[9] = 0.f;
        M[8] = dp[8];
        #pragma unroll
        for (int i = 7; i >= 1; i--) M[i] = dp[i] - cp[i] * M[i + 1];
        #pragma unroll
        for (int i = 0; i < 9; i++) {
            float a = (M[i + 1] - M[i]) * 1.5f;               // /(6h), h=1/9
            float bb = M[i] * 0.5f;
            float cc = (y[i + 1] - y[i]) * 9.f - (M[i + 1] + 2.f * M[i]) * (STEP_F / 6.f);
            float dd = y[i];
            coef[t][i] = a; coef[t][9 + i] = bb; coef[t][18 + i] = cc; coef[t][27 + i] = dd;
            coeff_out[t * 36 + i] = a;
            coeff_out[t * 36 + 9 + i] = bb;
            coeff_out[t * 36 + 18 + i] = cc;
            coeff_out[t * 36 + 27 + i] = dd;
        }
    }
    __syncthreads();

    for (int i = t; i < 24 * 255; i += 256) {
        int bc = i / 255, k = i - bc * 255;
        float xv = (float)k * (1.0f / 255.0f);
        float xi = floorf(xv * 9.0f);
        xi = fminf(fmaxf(xi, 0.f), 8.f);
        int ix = (int)xi;
        float xf = xv - xi * STEP_F;
        const float* cf = coef[bc];
        splines_out[i] = fmaf(fmaf(fmaf(cf[ix], xf, cf[9 + ix]), xf, cf[18 + ix]), xf, cf[27 + ix]);
    }
}

// ---------------------------------------------------------------------------
// Apply spline to full-res x. Output layout == input layout (NEXPERTS=1).
// One block covers 1024 consecutive floats; plane is uniform per block.
// ---------------------------------------------------------------------------
__global__ __launch_bounds__(256) void apply_k(const float* __restrict__ x,
                                               const float* __restrict__ coeff,
                                               float* __restrict__ out)
{
    __shared__ float cf[36];
    const int blk = blockIdx.x;
    const int plane = blk >> 10;           // 1024 blocks per 1M-float plane
    const int t = threadIdx.x;
    if (t < 36) cf[t] = coeff[plane * 36 + t];
    __syncthreads();

    size_t base = (size_t)blk * 1024 + (size_t)t * 4;
    float4 v = *(const float4*)(x + base);
    float4 o;
    #pragma unroll
    for (int k = 0; k < 4; k++) {
        float xv = (k == 0) ? v.x : (k == 1) ? v.y : (k == 2) ? v.z : v.w;
        float xi = floorf(xv * 9.0f);
        xi = fminf(fmaxf(xi, 0.f), 8.f);
        int ix = (int)xi;
        float xf = xv - xi * STEP_F;
        float r = fmaf(fmaf(fmaf(cf[ix], xf, cf[9 + ix]), xf, cf[18 + ix]), xf, cf[27 + ix]);
        if (k == 0) o.x = r; else if (k == 1) o.y = r; else if (k == 2) o.z = r; else o.w = r;
    }
    *(float4*)(out + base) = o;
}

// ---------------------------------------------------------------------------
extern "C" void kernel_launch(void* const* d_in, const int* in_sizes, int n_in,
                              void* d_out, int out_size, void* d_ws, size_t ws_size,
                              hipStream_t stream) {
    (void)in_sizes; (void)n_in; (void)out_size; (void)ws_size;

    const float* x    = (const float*)d_in[0];
    const float* w1   = (const float*)d_in[1];
    const float* b1   = (const float*)d_in[2];
    const float* w2   = (const float*)d_in[3];
    const float* b2   = (const float*)d_in[4];
    const float* g2   = (const float*)d_in[5];
    const float* be2  = (const float*)d_in[6];
    const float* w3   = (const float*)d_in[7];
    const float* b3   = (const float*)d_in[8];
    const float* g3   = (const float*)d_in[9];
    const float* be3  = (const float*)d_in[10];
    const float* w4   = (const float*)d_in[11];
    const float* b4   = (const float*)d_in[12];
    const float* g4   = (const float*)d_in[13];
    const float* be4  = (const float*)d_in[14];
    const float* w5   = (const float*)d_in[15];
    const float* b5   = (const float*)d_in[16];
    const float* g5   = (const float*)d_in[17];
    const float* be5  = (const float*)d_in[18];
    const float* fc1w = (const float*)d_in[19];
    const float* fc1b = (const float*)d_in[20];
    const float* fc2w = (const float*)d_in[21];
    const float* fc2b = (const float*)d_in[22];

    float* out = (float*)d_out;
    float* wsf = (float*)d_ws;

    // ws: stats + coeffs only (~10 KB)
    float* stats2 = wsf + 0;     // sum[16] @0, sumsq[16] @16
    float* stats3 = wsf + 32;    // sum[32], sumsq[32]
    float* stats4 = wsf + 96;    // sum[64], sumsq[64]
    float* stats5 = wsf + 224;   // sum[128], sumsq[128]
    float* spat5  = wsf + 480;   // [8*128]
    float* coeff  = wsf + 1504;  // [24*36]

    // big intermediates live in d_out's first ~40 MB (overwritten by apply_k)
    float* tmp = out;                  // 24*256*1024 = 6291456
    float* sm  = out + 6291456;        // 24*256*256  = 1572864
    float* h1  = out + 7864320;        // 8*8*127*127 = 1032256
    float* h2  = out + 8896576;        // 8*16*63*63  =  508032
    float* h3  = out + 9404608;        // 8*32*31*31  =  246016
    float* h4  = out + 9650624;        // 8*64*15*15  =  115200
    float* h5  = out + 9765824;        // 8*128*7*7   =   50176

    hipMemsetAsync(d_ws, 0, 480 * sizeof(float), stream);   // zero stats accumulators

    resize_v_k<<<24576, 256, 0, stream>>>(x, tmp);
    resize_h_k<<<6144, 256, 0, stream>>>(tmp, sm);

    conv_k<3, 8, 256, 127, 256, false, false, false>
        <<<dim3(64, 64), 256, 0, stream>>>(sm, w1, b1, nullptr, nullptr, nullptr, 0.f,
                                           h1, nullptr, nullptr, nullptr);
    conv_k<8, 16, 127, 63, 256, false, true, false>
        <<<dim3(16, 128), 256, 0, stream>>>(h1, w2, b2, nullptr, nullptr, nullptr, 0.f,
                                            h2, stats2, stats2 + 16, nullptr);
    conv_k<16, 32, 63, 31, 256, true, true, false>
        <<<dim3(4, 256), 256, 0, stream>>>(h2, w3, b3, g2, be2, stats2, 1.0f / 31752.0f,
                                           h3, stats3, stats3 + 32, nullptr);
    conv_k<32, 64, 31, 15, 256, true, true, false>
        <<<dim3(1, 512), 256, 0, stream>>>(h3, w4, b4, g3, be3, stats3, 1.0f / 7688.0f,
                                           h4, stats4, stats4 + 64, nullptr);
    conv_k<64, 128, 15, 7, 64, true, true, true>
        <<<dim3(1, 1024), 64, 0, stream>>>(h4, w5, b5, g4, be4, stats4, 1.0f / 1800.0f,
                                           h5, stats5, stats5 + 128, spat5);

    fc_spline_k<<<1, 256, 0, stream>>>(spat5, stats5, g5, be5,
                                       fc1w, fc1b, fc2w, fc2b,
                                       coeff, out + SPLINE_OFF);

    apply_k<<<24576, 256, 0, stream>>>(x, coeff, out);
}

// Round 2
// 166.174 us; speedup vs baseline: 1.0835x; 1.0835x over previous
//
#include <hip/hip_runtime.h>

#define SPLINE_OFF 25165824   // splines output offset (6120 floats follow)
#define STEP_F (1.0f/9.0f)

// ---------------------------------------------------------------------------
// Fused resize: jax.image.resize bilinear antialias, 1024 -> 256 (scale .25).
// Separable triangle kernel, 8 taps at stride 4, raw weights
// {1,3,5,7,7,5,3,1}/8, normalized by sum of valid taps (4.0 interior).
// One block per (plane, output-row): vertical pass (float4 coalesced global
// reads) -> LDS vsum[1024] -> horizontal pass -> sm. Identical FMA order to
// the verified two-pass version (bit-identical results).
// Block 0 additionally zeros the ws stats accumulators (runs before convs).
// ---------------------------------------------------------------------------
__global__ __launch_bounds__(256) void resize_k(const float* __restrict__ x,
                                                float* __restrict__ sm,
                                                float* __restrict__ wsz) {
    __shared__ float vsum[1024];
    const int blk = blockIdx.x;          // 24*256
    const int plane = blk >> 8;
    const int orow = blk & 255;
    const int t = threadIdx.x;
    if (blk == 0) {
        for (int i = t; i < 480; i += 256) wsz[i] = 0.f;
    }

    const float W[8] = {0.125f,0.375f,0.625f,0.875f,0.875f,0.625f,0.375f,0.125f};
    const float* p = x + (size_t)plane * 1048576 + t * 4;
    const int r0 = 4 * orow - 2;
    float ax = 0.f, ay = 0.f, az = 0.f, aw = 0.f;
    if (r0 >= 0 && r0 + 7 <= 1023) {
        #pragma unroll
        for (int k = 0; k < 8; k++) {
            const float4 v = *(const float4*)(p + (r0 + k) * 1024);
            const float w = W[k] * 0.25f;
            ax = fmaf(v.x, w, ax); ay = fmaf(v.y, w, ay);
            az = fmaf(v.z, w, az); aw = fmaf(v.w, w, aw);
        }
    } else {
        float wsum = 0.f;
        #pragma unroll
        for (int k = 0; k < 8; k++) {
            const int r = r0 + k;
            if (r >= 0 && r < 1024) {
                const float4 v = *(const float4*)(p + r * 1024);
                ax = fmaf(v.x, W[k], ax); ay = fmaf(v.y, W[k], ay);
                az = fmaf(v.z, W[k], az); aw = fmaf(v.w, W[k], aw);
                wsum += W[k];
            }
        }
        const float inv = 1.f / wsum;
        ax *= inv; ay *= inv; az *= inv; aw *= inv;
    }
    vsum[4 * t + 0] = ax; vsum[4 * t + 1] = ay;
    vsum[4 * t + 2] = az; vsum[4 * t + 3] = aw;
    __syncthreads();

    const int c0 = 4 * t - 2;
    float acc = 0.f;
    if (c0 >= 0 && c0 + 7 <= 1023) {
        #pragma unroll
        for (int k = 0; k < 8; k++)
            acc = fmaf(vsum[c0 + k], W[k] * 0.25f, acc);
    } else {
        float wsum = 0.f;
        #pragma unroll
        for (int k = 0; k < 8; k++) {
            const int c = c0 + k;
            if (c >= 0 && c < 1024) { acc = fmaf(vsum[c], W[k], acc); wsum += W[k]; }
        }
        acc /= wsum;
    }
    sm[(size_t)blk * 256 + t] = acc;
}

// ---------------------------------------------------------------------------
// Direct 3x3 stride-2 VALID conv + bias + ReLU.
//  - INBN: apply previous layer's batchnorm (scale/shift from accumulated
//          sum/sumsq stats) to the input on load.
//  - STATS: accumulate per-output-channel sum & sumsq of the ReLU output
//           (for this layer's BN, consumed by the NEXT kernel).
//  - SPATIAL: also write per-(b,co) spatial sum (requires gridDim.x == 1).
// blockIdx.y = b*COUT + co.
// ---------------------------------------------------------------------------
template<int CIN, int COUT, int INW, int OUTW, int BLOCK, bool INBN, bool STATS, bool SPATIAL>
__global__ __launch_bounds__(BLOCK) void conv_k(
    const float* __restrict__ in, const float* __restrict__ w,
    const float* __restrict__ bias,
    const float* __restrict__ g, const float* __restrict__ be,
    const float* __restrict__ inStats, float inInvN,
    float* __restrict__ out,
    float* __restrict__ gsum, float* __restrict__ gsumsq,
    float* __restrict__ spat)
{
    __shared__ float wsm[CIN * 9];
    __shared__ float scs[CIN];
    __shared__ float shs[CIN];
    __shared__ float red[2][BLOCK / 64];

    const int tid = threadIdx.x;
    const int bc = blockIdx.y;
    const int b  = bc / COUT;
    const int co = bc % COUT;

    for (int i = tid; i < CIN * 9; i += BLOCK) wsm[i] = w[co * CIN * 9 + i];
    if constexpr (INBN) {
        for (int ci = tid; ci < CIN; ci += BLOCK) {
            float s  = inStats[ci];
            float sq = inStats[CIN + ci];
            float m  = s * inInvN;
            float v  = sq * inInvN - m * m;
            float sc = g[ci] * rsqrtf(v + 1e-5f);
            scs[ci] = sc;
            shs[ci] = be[ci] - m * sc;
        }
    }
    __syncthreads();

    const int npix = OUTW * OUTW;
    const int p = blockIdx.x * BLOCK + tid;
    float val = 0.f;
    if (p < npix) {
        int oh = p / OUTW, ow = p % OUTW;
        float acc = bias[co];
        const float* ib = in + (size_t)(b * CIN) * INW * INW + (size_t)(2 * oh) * INW + 2 * ow;
        for (int ci = 0; ci < CIN; ci++) {
            const float* ip = ib + (size_t)ci * INW * INW;
            float sc = 1.f, sh = 0.f;
            if constexpr (INBN) { sc = scs[ci]; sh = shs[ci]; }
            #pragma unroll
            for (int kh = 0; kh < 3; kh++) {
                const float* r = ip + kh * INW;
                float x0 = r[0], x1 = r[1], x2 = r[2];
                if constexpr (INBN) {
                    x0 = fmaf(x0, sc, sh); x1 = fmaf(x1, sc, sh); x2 = fmaf(x2, sc, sh);
                }
                acc = fmaf(x0, wsm[ci * 9 + kh * 3 + 0], acc);
                acc = fmaf(x1, wsm[ci * 9 + kh * 3 + 1], acc);
                acc = fmaf(x2, wsm[ci * 9 + kh * 3 + 2], acc);
            }
        }
        val = fmaxf(acc, 0.f);
        out[(size_t)bc * npix + p] = val;
    }

    if constexpr (STATS) {
        float s = val, sq = val * val;
        #pragma unroll
        for (int off = 32; off > 0; off >>= 1) {
            s  += __shfl_down(s, off);
            sq += __shfl_down(sq, off);
        }
        int wid = tid >> 6, lane = tid & 63;
        if (lane == 0) { red[0][wid] = s; red[1][wid] = sq; }
        __syncthreads();
        if (tid == 0) {
            float ts = 0.f, tq = 0.f;
            #pragma unroll
            for (int i = 0; i < BLOCK / 64; i++) { ts += red[0][i]; tq += red[1][i]; }
            atomicAdd(&gsum[co], ts);
            atomicAdd(&gsumsq[co], tq);
            if constexpr (SPATIAL) spat[bc] = ts;   // gridDim.x == 1 here
        }
    }
}

// ---------------------------------------------------------------------------
// Single-block: BN5 finalize -> spatial mean -> fc1(ReLU) -> fc2 -> +identity
// -> natural cubic spline coefficients (Thomas solve) -> write coeffs + the
// 255-point "splines" output.
// ---------------------------------------------------------------------------
__global__ __launch_bounds__(256) void fc_spline_k(
    const float* __restrict__ spat5, const float* __restrict__ stats5,
    const float* __restrict__ g5, const float* __restrict__ be5,
    const float* __restrict__ fc1w, const float* __restrict__ fc1b,
    const float* __restrict__ fc2w, const float* __restrict__ fc2b,
    float* __restrict__ coeff_out, float* __restrict__ splines_out)
{
    __shared__ float sc5[128], sh5[128];
    __shared__ float h[1024];     // [b][c] b<8, c<128
    __shared__ float h1v[1024];
    __shared__ float ysn[240];    // [bc][10], bc = b*3+cch
    __shared__ float coef[24][36];

    const int t = threadIdx.x;

    if (t < 128) {
        float m = stats5[t] * (1.f / 392.f);
        float v = stats5[128 + t] * (1.f / 392.f) - m * m;
        float sc = g5[t] * rsqrtf(v + 1e-5f);
        sc5[t] = sc;
        sh5[t] = be5[t] - m * sc;
    }
    __syncthreads();

    for (int i = t; i < 1024; i += 256) {
        int c = i & 127;
        h[i] = fmaf(sc5[c], spat5[i] * (1.f / 49.f), sh5[c]);
    }
    __syncthreads();

    for (int i = t; i < 1024; i += 256) {
        int b = i >> 7, j = i & 127;
        float acc = fc1b[j];
        for (int c = 0; c < 128; c++)
            acc = fmaf(h[(b << 7) + c], fc1w[(j << 7) + c], acc);
        h1v[i] = fmaxf(acc, 0.f);
    }
    __syncthreads();

    if (t < 240) {
        int b = t / 30, k = t % 30;
        float acc = fc2b[k];
        for (int j = 0; j < 128; j++)
            acc = fmaf(h1v[(b << 7) + j], fc2w[(k << 7) + j], acc);
        ysn[t] = acc + (float)(k % 10) * STEP_F;   // + identity ramp
    }
    __syncthreads();

    if (t < 24) {
        float y[10];
        #pragma unroll
        for (int i = 0; i < 10; i++) y[i] = ysn[t * 10 + i];
        // Thomas solve: M[i-1] + 4 M[i] + M[i+1] = 486*(y[i-1]-2y[i]+y[i+1]),
        // i=1..8, M[0]=M[9]=0   (486 = 6/h^2, h = 1/9)
        float rhs[9], cp[9], dp[9];
        #pragma unroll
        for (int i = 1; i <= 8; i++)
            rhs[i] = 486.f * (y[i - 1] - 2.f * y[i] + y[i + 1]);
        cp[1] = 0.25f; dp[1] = rhs[1] * 0.25f;
        #pragma unroll
        for (int i = 2; i <= 8; i++) {
            float m = 1.f / (4.f - cp[i - 1]);
            cp[i] = m;
            dp[i] = (rhs[i] - dp[i - 1]) * m;
        }
        float M[10];
        M[0] = 0.f; M[9] = 0.f;
        M[8] = dp[8];
        #pragma unroll
        for (int i = 7; i >= 1; i--) M[i] = dp[i] - cp[i] * M[i + 1];
        #pragma unroll
        for (int i = 0; i < 9; i++) {
            float a = (M[i + 1] - M[i]) * 1.5f;               // /(6h), h=1/9
            float bb = M[i] * 0.5f;
            float cc = (y[i + 1] - y[i]) * 9.f - (M[i + 1] + 2.f * M[i]) * (STEP_F / 6.f);
            float dd = y[i];
            coef[t][i] = a; coef[t][9 + i] = bb; coef[t][18 + i] = cc; coef[t][27 + i] = dd;
            coeff_out[t * 36 + i] = a;
            coeff_out[t * 36 + 9 + i] = bb;
            coeff_out[t * 36 + 18 + i] = cc;
            coeff_out[t * 36 + 27 + i] = dd;
        }
    }
    __syncthreads();

    for (int i = t; i < 24 * 255; i += 256) {
        int bc = i / 255, k = i - bc * 255;
        float xv = (float)k * (1.0f / 255.0f);
        float xi = floorf(xv * 9.0f);
        xi = fminf(fmaxf(xi, 0.f), 8.f);
        int ix = (int)xi;
        float xf = xv - xi * STEP_F;
        const float* cf = coef[bc];
        splines_out[i] = fmaf(fmaf(fmaf(cf[ix], xf, cf[9 + ix]), xf, cf[18 + ix]), xf, cf[27 + ix]);
    }
}

// ---------------------------------------------------------------------------
// Apply spline to full-res x. Output layout == input layout (NEXPERTS=1).
// One block covers 1024 consecutive floats; plane is uniform per block.
// ---------------------------------------------------------------------------
__global__ __launch_bounds__(256) void apply_k(const float* __restrict__ x,
                                               const float* __restrict__ coeff,
                                               float* __restrict__ out)
{
    __shared__ float cf[36];
    const int blk = blockIdx.x;
    const int plane = blk >> 10;           // 1024 blocks per 1M-float plane
    const int t = threadIdx.x;
    if (t < 36) cf[t] = coeff[plane * 36 + t];
    __syncthreads();

    size_t base = (size_t)blk * 1024 + (size_t)t * 4;
    float4 v = *(const float4*)(x + base);
    float4 o;
    #pragma unroll
    for (int k = 0; k < 4; k++) {
        float xv = (k == 0) ? v.x : (k == 1) ? v.y : (k == 2) ? v.z : v.w;
        float xi = floorf(xv * 9.0f);
        xi = fminf(fmaxf(xi, 0.f), 8.f);
        int ix = (int)xi;
        float xf = xv - xi * STEP_F;
        float r = fmaf(fmaf(fmaf(cf[ix], xf, cf[9 + ix]), xf, cf[18 + ix]), xf, cf[27 + ix]);
        if (k == 0) o.x = r; else if (k == 1) o.y = r; else if (k == 2) o.z = r; else o.w = r;
    }
    *(float4*)(out + base) = o;
}

// ---------------------------------------------------------------------------
extern "C" void kernel_launch(void* const* d_in, const int* in_sizes, int n_in,
                              void* d_out, int out_size, void* d_ws, size_t ws_size,
                              hipStream_t stream) {
    (void)in_sizes; (void)n_in; (void)out_size; (void)ws_size;

    const float* x    = (const float*)d_in[0];
    const float* w1   = (const float*)d_in[1];
    const float* b1   = (const float*)d_in[2];
    const float* w2   = (const float*)d_in[3];
    const float* b2   = (const float*)d_in[4];
    const float* g2   = (const float*)d_in[5];
    const float* be2  = (const float*)d_in[6];
    const float* w3   = (const float*)d_in[7];
    const float* b3   = (const float*)d_in[8];
    const float* g3   = (const float*)d_in[9];
    const float* be3  = (const float*)d_in[10];
    const float* w4   = (const float*)d_in[11];
    const float* b4   = (const float*)d_in[12];
    const float* g4   = (const float*)d_in[13];
    const float* be4  = (const float*)d_in[14];
    const float* w5   = (const float*)d_in[15];
    const float* b5   = (const float*)d_in[16];
    const float* g5   = (const float*)d_in[17];
    const float* be5  = (const float*)d_in[18];
    const float* fc1w = (const float*)d_in[19];
    const float* fc1b = (const float*)d_in[20];
    const float* fc2w = (const float*)d_in[21];
    const float* fc2b = (const float*)d_in[22];

    float* out = (float*)d_out;
    float* wsf = (float*)d_ws;

    // ws: stats + coeffs only (~10 KB); zeroed by resize_k block 0
    float* stats2 = wsf + 0;     // sum[16] @0, sumsq[16] @16
    float* stats3 = wsf + 32;    // sum[32], sumsq[32]
    float* stats4 = wsf + 96;    // sum[64], sumsq[64]
    float* stats5 = wsf + 224;   // sum[128], sumsq[128]
    float* spat5  = wsf + 480;   // [8*128]
    float* coeff  = wsf + 1504;  // [24*36]

    // big intermediates live in d_out's first ~14 MB (overwritten by apply_k)
    float* sm  = out;                  // 24*256*256  = 1572864
    float* h1  = out + 1572864;        // 8*8*127*127 = 1032256
    float* h2  = out + 2605120;        // 8*16*63*63  =  508032
    float* h3  = out + 3113152;        // 8*32*31*31  =  246016
    float* h4  = out + 3359168;        // 8*64*15*15  =  115200
    float* h5  = out + 3474368;        // 8*128*7*7   =   50176

    resize_k<<<6144, 256, 0, stream>>>(x, sm, wsf);

    conv_k<3, 8, 256, 127, 256, false, false, false>
        <<<dim3(64, 64), 256, 0, stream>>>(sm, w1, b1, nullptr, nullptr, nullptr, 0.f,
                                           h1, nullptr, nullptr, nullptr);
    conv_k<8, 16, 127, 63, 256, false, true, false>
        <<<dim3(16, 128), 256, 0, stream>>>(h1, w2, b2, nullptr, nullptr, nullptr, 0.f,
                                            h2, stats2, stats2 + 16, nullptr);
    conv_k<16, 32, 63, 31, 256, true, true, false>
        <<<dim3(4, 256), 256, 0, stream>>>(h2, w3, b3, g2, be2, stats2, 1.0f / 31752.0f,
                                           h3, stats3, stats3 + 32, nullptr);
    conv_k<32, 64, 31, 15, 256, true, true, false>
        <<<dim3(1, 512), 256, 0, stream>>>(h3, w4, b4, g3, be3, stats3, 1.0f / 7688.0f,
                                           h4, stats4, stats4 + 64, nullptr);
    conv_k<64, 128, 15, 7, 64, true, true, true>
        <<<dim3(1, 1024), 64, 0, stream>>>(h4, w5, b5, g4, be4, stats4, 1.0f / 1800.0f,
                                           h5, stats5, stats5 + 128, spat5);

    fc_spline_k<<<1, 256, 0, stream>>>(spat5, stats5, g5, be5,
                                       fc1w, fc1b, fc2w, fc2b,
                                       coeff, out + SPLINE_OFF);

    apply_k<<<24576, 256, 0, stream>>>(x, coeff, out);
}

// Round 3
// 157.430 us; speedup vs baseline: 1.1437x; 1.0555x over previous
//
#include <hip/hip_runtime.h>

#define SPLINE_OFF 25165824   // splines output offset (6120 floats follow)
#define STEP_F (1.0f/9.0f)

// ---------------------------------------------------------------------------
// Fused resize: jax.image.resize bilinear antialias, 1024 -> 256 (scale .25).
// Separable triangle kernel, 8 taps at stride 4, raw weights
// {1,3,5,7,7,5,3,1}/8, normalized by sum of valid taps (4.0 interior).
// One block per (plane, output-row). Block 0 zeros ws stats accumulators.
// ---------------------------------------------------------------------------
__global__ __launch_bounds__(256) void resize_k(const float* __restrict__ x,
                                                float* __restrict__ sm,
                                                float* __restrict__ wsz) {
    __shared__ float vsum[1024];
    const int blk = blockIdx.x;          // 24*256
    const int plane = blk >> 8;
    const int orow = blk & 255;
    const int t = threadIdx.x;
    if (blk == 0) {
        for (int i = t; i < 480; i += 256) wsz[i] = 0.f;
    }

    const float W[8] = {0.125f,0.375f,0.625f,0.875f,0.875f,0.625f,0.375f,0.125f};
    const float* p = x + (size_t)plane * 1048576 + t * 4;
    const int r0 = 4 * orow - 2;
    float ax = 0.f, ay = 0.f, az = 0.f, aw = 0.f;
    if (r0 >= 0 && r0 + 7 <= 1023) {
        #pragma unroll
        for (int k = 0; k < 8; k++) {
            const float4 v = *(const float4*)(p + (r0 + k) * 1024);
            const float w = W[k] * 0.25f;
            ax = fmaf(v.x, w, ax); ay = fmaf(v.y, w, ay);
            az = fmaf(v.z, w, az); aw = fmaf(v.w, w, aw);
        }
    } else {
        float wsum = 0.f;
        #pragma unroll
        for (int k = 0; k < 8; k++) {
            const int r = r0 + k;
            if (r >= 0 && r < 1024) {
                const float4 v = *(const float4*)(p + r * 1024);
                ax = fmaf(v.x, W[k], ax); ay = fmaf(v.y, W[k], ay);
                az = fmaf(v.z, W[k], az); aw = fmaf(v.w, W[k], aw);
                wsum += W[k];
            }
        }
        const float inv = 1.f / wsum;
        ax *= inv; ay *= inv; az *= inv; aw *= inv;
    }
    vsum[4 * t + 0] = ax; vsum[4 * t + 1] = ay;
    vsum[4 * t + 2] = az; vsum[4 * t + 3] = aw;
    __syncthreads();

    const int c0 = 4 * t - 2;
    float acc = 0.f;
    if (c0 >= 0 && c0 + 7 <= 1023) {
        #pragma unroll
        for (int k = 0; k < 8; k++)
            acc = fmaf(vsum[c0 + k], W[k] * 0.25f, acc);
    } else {
        float wsum = 0.f;
        #pragma unroll
        for (int k = 0; k < 8; k++) {
            const int c = c0 + k;
            if (c >= 0 && c < 1023 + 1) { if (c >= 0 && c < 1024) { acc = fmaf(vsum[c], W[k], acc); wsum += W[k]; } }
        }
        acc /= wsum;
    }
    sm[(size_t)blk * 256 + t] = acc;
}

// ---------------------------------------------------------------------------
// Direct 3x3 stride-2 VALID conv + bias + ReLU, restructured for latency:
//  - NCO output channels per thread (input loads shared across NCO accs)
//  - CISPLIT-way input-channel split with LDS reduction (short serial chains)
//  - BN of the PREVIOUS layer folded into the staged weights:
//      conv(sc*x+sh) = conv_{w*sc}(x) + C,  C[co] = bias + sum_ci sh_ci*rowsum
//  - STATS: per-co sum/sumsq of ReLU output via atomics (for next layer's BN)
//  - SPATIAL: per-(b,co) spatial sum (requires gridDim.x==1)
//  - WRITE=false skips storing the activation (conv5: only stats are used)
// Grid: (ceil(npix/PIX), B * COUT/NCO). Block: PIX*CISPLIT threads.
// ---------------------------------------------------------------------------
template<int CIN, int COUT, int INW, int OUTW, int NCO, int CISPLIT, int PIX,
         bool INBN, bool STATS, bool SPATIAL, bool WRITE>
__global__ __launch_bounds__(PIX * CISPLIT) void conv_k(
    const float* __restrict__ in, const float* __restrict__ w,
    const float* __restrict__ bias,
    const float* __restrict__ g, const float* __restrict__ be,
    const float* __restrict__ inStats, float inInvN,
    float* __restrict__ out,
    float* __restrict__ gsum, float* __restrict__ gsumsq,
    float* __restrict__ spat)
{
    constexpr int BLOCK = PIX * CISPLIT;
    constexpr int CPS = CIN / CISPLIT;
    constexpr int COG = COUT / NCO;

    __shared__ float wsm[NCO][CIN * 9];
    __shared__ float scs[CIN], shs[CIN];
    __shared__ float wrow[NCO][CIN];
    __shared__ float cadd[NCO];
    __shared__ float part[CISPLIT][PIX][NCO];
    __shared__ float red[NCO][2][PIX / 64];

    const int tid = threadIdx.x;
    const int p   = tid & (PIX - 1);
    const int cs  = tid / PIX;
    const int bc  = blockIdx.y;
    const int b   = bc / COG;
    const int co0 = (bc % COG) * NCO;

    if constexpr (INBN) {
        for (int ci = tid; ci < CIN; ci += BLOCK) {
            float s  = inStats[ci];
            float sq = inStats[CIN + ci];
            float m  = s * inInvN;
            float v  = sq * inInvN - m * m;
            float sc = g[ci] * rsqrtf(v + 1e-5f);
            scs[ci] = sc;
            shs[ci] = be[ci] - m * sc;
        }
        __syncthreads();
    }

    // stage weights (pre-scaled by BN sc) + raw row-sums for the constant
    for (int i = tid; i < NCO * CIN * 9; i += BLOCK) {
        int n = i / (CIN * 9), r = i - n * (CIN * 9), ci = r / 9;
        float wv = w[(co0 + n) * CIN * 9 + r];
        wsm[n][r] = INBN ? wv * scs[ci] : wv;
    }
    if constexpr (INBN) {
        for (int i = tid; i < NCO * CIN; i += BLOCK) {
            int n = i / CIN, ci = i - n * CIN;
            const float* wp = w + ((co0 + n) * CIN + ci) * 9;
            float s = 0.f;
            #pragma unroll
            for (int k = 0; k < 9; k++) s += wp[k];
            wrow[n][ci] = s;
        }
    }
    __syncthreads();
    if (tid < NCO) {
        float c = bias[co0 + tid];
        if constexpr (INBN) {
            for (int ci = 0; ci < CIN; ci++) c = fmaf(wrow[tid][ci], shs[ci], c);
        }
        cadd[tid] = c;
    }
    __syncthreads();

    const int npix = OUTW * OUTW;
    const int pg = blockIdx.x * PIX + p;
    float acc[NCO];
    #pragma unroll
    for (int n = 0; n < NCO; n++) acc[n] = 0.f;

    if (pg < npix) {
        const int oh = pg / OUTW, ow = pg - oh * OUTW;
        const float* ib = in + ((size_t)(b * CIN) + cs * CPS) * INW * INW
                             + (size_t)(2 * oh) * INW + 2 * ow;
        for (int ci = 0; ci < CPS; ci++) {
            const float* ip = ib + (size_t)ci * INW * INW;
            const int cw = (cs * CPS + ci) * 9;
            #pragma unroll
            for (int kh = 0; kh < 3; kh++) {
                const float* r = ip + kh * INW;
                #pragma unroll
                for (int kw = 0; kw < 3; kw++) {
                    const float xv = r[kw];
                    #pragma unroll
                    for (int n = 0; n < NCO; n++)
                        acc[n] = fmaf(xv, wsm[n][cw + kh * 3 + kw], acc[n]);
                }
            }
        }
    }

    float val[NCO];
    #pragma unroll
    for (int n = 0; n < NCO; n++) val[n] = 0.f;

    if constexpr (CISPLIT > 1) {
        #pragma unroll
        for (int n = 0; n < NCO; n++) part[cs][p][n] = acc[n];
        __syncthreads();
    }

    if (cs == 0) {
        #pragma unroll
        for (int n = 0; n < NCO; n++) {
            float s = acc[n];
            if constexpr (CISPLIT > 1) {
                #pragma unroll
                for (int q = 1; q < CISPLIT; q++) s += part[q][p][n];
            }
            if (pg < npix) {
                val[n] = fmaxf(s + cadd[n], 0.f);
                if constexpr (WRITE)
                    out[(size_t)(b * COUT + co0 + n) * npix + pg] = val[n];
            }
        }
    }

    if constexpr (STATS) {
        if (cs == 0) {
            #pragma unroll
            for (int n = 0; n < NCO; n++) {
                float s = val[n], sq = val[n] * val[n];
                #pragma unroll
                for (int off = 32; off > 0; off >>= 1) {
                    s  += __shfl_down(s, off);
                    sq += __shfl_down(sq, off);
                }
                if ((tid & 63) == 0) { red[n][0][tid >> 6] = s; red[n][1][tid >> 6] = sq; }
            }
        }
        __syncthreads();
        if (tid == 0) {
            #pragma unroll
            for (int n = 0; n < NCO; n++) {
                float ts = 0.f, tq = 0.f;
                #pragma unroll
                for (int i = 0; i < PIX / 64; i++) { ts += red[n][0][i]; tq += red[n][1][i]; }
                atomicAdd(&gsum[co0 + n], ts);
                atomicAdd(&gsumsq[co0 + n], tq);
                if constexpr (SPATIAL) spat[b * COUT + co0 + n] = ts;
            }
        }
    }
}

// ---------------------------------------------------------------------------
// Single-block: BN5 finalize -> spatial mean -> fc1(ReLU) -> fc2 -> +identity
// -> natural cubic spline coefficients (Thomas solve) -> coeffs + splines.
// ---------------------------------------------------------------------------
__global__ __launch_bounds__(256) void fc_spline_k(
    const float* __restrict__ spat5, const float* __restrict__ stats5,
    const float* __restrict__ g5, const float* __restrict__ be5,
    const float* __restrict__ fc1w, const float* __restrict__ fc1b,
    const float* __restrict__ fc2w, const float* __restrict__ fc2b,
    float* __restrict__ coeff_out, float* __restrict__ splines_out)
{
    __shared__ float sc5[128], sh5[128];
    __shared__ float h[1024];     // [b][c] b<8, c<128
    __shared__ float h1v[1024];
    __shared__ float ysn[240];    // [bc][10], bc = b*3+cch
    __shared__ float coef[24][36];

    const int t = threadIdx.x;

    if (t < 128) {
        float m = stats5[t] * (1.f / 392.f);
        float v = stats5[128 + t] * (1.f / 392.f) - m * m;
        float sc = g5[t] * rsqrtf(v + 1e-5f);
        sc5[t] = sc;
        sh5[t] = be5[t] - m * sc;
    }
    __syncthreads();

    for (int i = t; i < 1024; i += 256) {
        int c = i & 127;
        h[i] = fmaf(sc5[c], spat5[i] * (1.f / 49.f), sh5[c]);
    }
    __syncthreads();

    for (int i = t; i < 1024; i += 256) {
        int b = i >> 7, j = i & 127;
        float acc = fc1b[j];
        for (int c = 0; c < 128; c++)
            acc = fmaf(h[(b << 7) + c], fc1w[(j << 7) + c], acc);
        h1v[i] = fmaxf(acc, 0.f);
    }
    __syncthreads();

    if (t < 240) {
        int b = t / 30, k = t % 30;
        float acc = fc2b[k];
        for (int j = 0; j < 128; j++)
            acc = fmaf(h1v[(b << 7) + j], fc2w[(k << 7) + j], acc);
        ysn[t] = acc + (float)(k % 10) * STEP_F;   // + identity ramp
    }
    __syncthreads();

    if (t < 24) {
        float y[10];
        #pragma unroll
        for (int i = 0; i < 10; i++) y[i] = ysn[t * 10 + i];
        // Thomas solve: M[i-1] + 4 M[i] + M[i+1] = 486*(y[i-1]-2y[i]+y[i+1])
        float rhs[9], cp[9], dp[9];
        #pragma unroll
        for (int i = 1; i <= 8; i++)
            rhs[i] = 486.f * (y[i - 1] - 2.f * y[i] + y[i + 1]);
        cp[1] = 0.25f; dp[1] = rhs[1] * 0.25f;
        #pragma unroll
        for (int i = 2; i <= 8; i++) {
            float m = 1.f / (4.f - cp[i - 1]);
            cp[i] = m;
            dp[i] = (rhs[i] - dp[i - 1]) * m;
        }
        float M[10];
        M[0] = 0.f; M[9] = 0.f;
        M[8] = dp[8];
        #pragma unroll
        for (int i = 7; i >= 1; i--) M[i] = dp[i] - cp[i] * M[i + 1];
        #pragma unroll
        for (int i = 0; i < 9; i++) {
            float a = (M[i + 1] - M[i]) * 1.5f;               // /(6h), h=1/9
            float bb = M[i] * 0.5f;
            float cc = (y[i + 1] - y[i]) * 9.f - (M[i + 1] + 2.f * M[i]) * (STEP_F / 6.f);
            float dd = y[i];
            coef[t][i] = a; coef[t][9 + i] = bb; coef[t][18 + i] = cc; coef[t][27 + i] = dd;
            coeff_out[t * 36 + i] = a;
            coeff_out[t * 36 + 9 + i] = bb;
            coeff_out[t * 36 + 18 + i] = cc;
            coeff_out[t * 36 + 27 + i] = dd;
        }
    }
    __syncthreads();

    for (int i = t; i < 24 * 255; i += 256) {
        int bc = i / 255, k = i - bc * 255;
        float xv = (float)k * (1.0f / 255.0f);
        float xi = floorf(xv * 9.0f);
        xi = fminf(fmaxf(xi, 0.f), 8.f);
        int ix = (int)xi;
        float xf = xv - xi * STEP_F;
        const float* cf = coef[bc];
        splines_out[i] = fmaf(fmaf(fmaf(cf[ix], xf, cf[9 + ix]), xf, cf[18 + ix]), xf, cf[27 + ix]);
    }
}

// ---------------------------------------------------------------------------
// Apply spline to full-res x. One block = 1024 consecutive floats.
// ---------------------------------------------------------------------------
__global__ __launch_bounds__(256) void apply_k(const float* __restrict__ x,
                                               const float* __restrict__ coeff,
                                               float* __restrict__ out)
{
    __shared__ float cf[36];
    const int blk = blockIdx.x;
    const int plane = blk >> 10;           // 1024 blocks per 1M-float plane
    const int t = threadIdx.x;
    if (t < 36) cf[t] = coeff[plane * 36 + t];
    __syncthreads();

    size_t base = (size_t)blk * 1024 + (size_t)t * 4;
    float4 v = *(const float4*)(x + base);
    float4 o;
    #pragma unroll
    for (int k = 0; k < 4; k++) {
        float xv = (k == 0) ? v.x : (k == 1) ? v.y : (k == 2) ? v.z : v.w;
        float xi = floorf(xv * 9.0f);
        xi = fminf(fmaxf(xi, 0.f), 8.f);
        int ix = (int)xi;
        float xf = xv - xi * STEP_F;
        float r = fmaf(fmaf(fmaf(cf[ix], xf, cf[9 + ix]), xf, cf[18 + ix]), xf, cf[27 + ix]);
        if (k == 0) o.x = r; else if (k == 1) o.y = r; else if (k == 2) o.z = r; else o.w = r;
    }
    *(float4*)(out + base) = o;
}

// ---------------------------------------------------------------------------
extern "C" void kernel_launch(void* const* d_in, const int* in_sizes, int n_in,
                              void* d_out, int out_size, void* d_ws, size_t ws_size,
                              hipStream_t stream) {
    (void)in_sizes; (void)n_in; (void)out_size; (void)ws_size;

    const float* x    = (const float*)d_in[0];
    const float* w1   = (const float*)d_in[1];
    const float* b1   = (const float*)d_in[2];
    const float* w2   = (const float*)d_in[3];
    const float* b2   = (const float*)d_in[4];
    const float* g2   = (const float*)d_in[5];
    const float* be2  = (const float*)d_in[6];
    const float* w3   = (const float*)d_in[7];
    const float* b3   = (const float*)d_in[8];
    const float* g3   = (const float*)d_in[9];
    const float* be3  = (const float*)d_in[10];
    const float* w4   = (const float*)d_in[11];
    const float* b4   = (const float*)d_in[12];
    const float* g4   = (const float*)d_in[13];
    const float* be4  = (const float*)d_in[14];
    const float* w5   = (const float*)d_in[15];
    const float* b5   = (const float*)d_in[16];
    const float* g5   = (const float*)d_in[17];
    const float* be5  = (const float*)d_in[18];
    const float* fc1w = (const float*)d_in[19];
    const float* fc1b = (const float*)d_in[20];
    const float* fc2w = (const float*)d_in[21];
    const float* fc2b = (const float*)d_in[22];

    float* out = (float*)d_out;
    float* wsf = (float*)d_ws;

    // ws: stats + coeffs only (~10 KB); zeroed by resize_k block 0
    float* stats2 = wsf + 0;     // sum[16] @0, sumsq[16] @16
    float* stats3 = wsf + 32;    // sum[32], sumsq[32]
    float* stats4 = wsf + 96;    // sum[64], sumsq[64]
    float* stats5 = wsf + 224;   // sum[128], sumsq[128]
    float* spat5  = wsf + 480;   // [8*128]
    float* coeff  = wsf + 1504;  // [24*36]

    // big intermediates live in d_out's first ~14 MB (overwritten by apply_k)
    float* sm  = out;                  // 24*256*256  = 1572864
    float* h1  = out + 1572864;        // 8*8*127*127 = 1032256
    float* h2  = out + 2605120;        // 8*16*63*63  =  508032
    float* h3  = out + 3113152;        // 8*32*31*31  =  246016
    float* h4  = out + 3359168;        // 8*64*15*15  =  115200

    resize_k<<<6144, 256, 0, stream>>>(x, sm, wsf);

    // conv1: 3->8, 256->127
    conv_k<3, 8, 256, 127, 2, 1, 256, false, false, false, true>
        <<<dim3(64, 32), 256, 0, stream>>>(sm, w1, b1, nullptr, nullptr, nullptr, 0.f,
                                           h1, nullptr, nullptr, nullptr);
    // conv2: 8->16, 127->63 (+stats2)
    conv_k<8, 16, 127, 63, 2, 1, 256, false, true, false, true>
        <<<dim3(16, 64), 256, 0, stream>>>(h1, w2, b2, nullptr, nullptr, nullptr, 0.f,
                                           h2, stats2, stats2 + 16, nullptr);
    // conv3: 16->32, 63->31 (BN2 folded, +stats3)
    conv_k<16, 32, 63, 31, 2, 1, 256, true, true, false, true>
        <<<dim3(4, 128), 256, 0, stream>>>(h2, w3, b3, g2, be2, stats2, 1.0f / 31752.0f,
                                           h3, stats3, stats3 + 32, nullptr);
    // conv4: 32->64, 31->15 (BN3 folded, +stats4, ci-split 2)
    conv_k<32, 64, 31, 15, 2, 2, 256, true, true, false, true>
        <<<dim3(1, 256), 512, 0, stream>>>(h3, w4, b4, g3, be3, stats3, 1.0f / 7688.0f,
                                           h4, stats4, stats4 + 64, nullptr);
    // conv5: 64->128, 15->7 (BN4 folded, +stats5 +spat5, ci-split 4, no store)
    conv_k<64, 128, 15, 7, 2, 4, 64, true, true, true, false>
        <<<dim3(1, 512), 256, 0, stream>>>(h4, w5, b5, g4, be4, stats4, 1.0f / 1800.0f,
                                           nullptr, stats5, stats5 + 128, spat5);

    fc_spline_k<<<1, 256, 0, stream>>>(spat5, stats5, g5, be5,
                                       fc1w, fc1b, fc2w, fc2b,
                                       coeff, out + SPLINE_OFF);

    apply_k<<<24576, 256, 0, stream>>>(x, coeff, out);
}